// Round 3
// baseline (107.828 us; speedup 1.0000x reference)
//
#include <hip/hip_runtime.h>
#include <hip/hip_bf16.h>

#define B_    512
#define F_    128
#define NTRIP 1024
#define MARGIN 1.0f
#define NBLK  32      // 512/16 pair-blocks per dim
#define NGRID 264     // k_pair grid: each block folds 2 pair-blocks

// ws layout (floats)
#define OFF_M    0            // 128*512
#define OFF_G    65536        // 128
#define OFF_TL   65664        // 4 triplet partials
#define OFF_CNT  65672        // ticket counter (as int)
#define OFF_S    65680        // 128*128
#define OFF_PART 82064        // 264*16384  (~17.6 MB)

typedef __attribute__((ext_vector_type(8))) short bf16x8;
typedef __attribute__((ext_vector_type(4))) float f32x4;

#define LDS_ROW 20   // dwords per Dt row: 32 bf16 = 16 dwords, +4 pad (80 B)

__device__ inline unsigned int bf16r(float f) {   // RNE float->bf16 (f>=0, finite)
    unsigned int u = __float_as_uint(f);
    u += 0x7FFFu + ((u >> 16) & 1u);
    return u >> 16;
}

// ------------- prep: blocks 0..127 = m/g per feature; 128..131 = triplet ----
__global__ __launch_bounds__(256) void k_prep(const float* __restrict__ emb,
                                              const int* __restrict__ trip,
                                              float* __restrict__ m,
                                              float* __restrict__ g,
                                              float* __restrict__ tl,
                                              int* __restrict__ cnt) {
    const int bid = blockIdx.x;
    const int t   = threadIdx.x;
    if (bid < 128) {
        if (bid == 0 && t == 0) *cnt = 0;      // reset ticket for k_S_final
        const int i = bid;                      // feature
        __shared__ float x[B_];
        x[t]       = emb[t * F_ + i];
        x[t + 256] = emb[(t + 256) * F_ + i];
        __syncthreads();
        float xa0 = x[t], xa1 = x[t + 256];
        float s0 = 0.f, s1 = 0.f;
        #pragma unroll 4
        for (int b = 0; b < B_; ++b) {
            float xb = x[b];
            s0 += fabsf(xa0 - xb);
            s1 += fabsf(xa1 - xb);
        }
        m[i * B_ + t]       = s0 * (1.0f / B_);
        m[i * B_ + t + 256] = s1 * (1.0f / B_);
        __shared__ float red[256];
        red[t] = s0 + s1;
        __syncthreads();
        for (int s = 128; s > 0; s >>= 1) {
            if (t < s) red[t] += red[t + s];
            __syncthreads();
        }
        if (t == 0) g[i] = red[0] * (1.0f / ((float)B_ * (float)B_));
    } else {
        const int tt = (bid - 128) * 256 + t;   // triplet id 0..1023
        int a = trip[3 * tt]     & (B_ - 1);
        int p = trip[3 * tt + 1] & (B_ - 1);
        int n = trip[3 * tt + 2] & (B_ - 1);
        const float4* ea = reinterpret_cast<const float4*>(emb + a * F_);
        const float4* ep = reinterpret_cast<const float4*>(emb + p * F_);
        const float4* en = reinterpret_cast<const float4*>(emb + n * F_);
        float ap = 0.f, an = 0.f;
        #pragma unroll 8
        for (int f4 = 0; f4 < F_ / 4; ++f4) {
            float4 va = ea[f4], vp = ep[f4], vn = en[f4];
            float d;
            d = va.x - vp.x; ap = fmaf(d, d, ap);
            d = va.y - vp.y; ap = fmaf(d, d, ap);
            d = va.z - vp.z; ap = fmaf(d, d, ap);
            d = va.w - vp.w; ap = fmaf(d, d, ap);
            d = va.x - vn.x; an = fmaf(d, d, an);
            d = va.y - vn.y; an = fmaf(d, d, an);
            d = va.z - vn.z; an = fmaf(d, d, an);
            d = va.w - vn.w; an = fmaf(d, d, an);
        }
        float l = ap - an + MARGIN;
        l = l > 0.f ? l : 0.f;
        __shared__ float red[256];
        red[t] = l;
        __syncthreads();
        for (int s = 128; s > 0; s >>= 1) {
            if (t < s) red[t] += red[t + s];
            __syncthreads();
        }
        if (t == 0) tl[bid - 128] = red[0];
    }
}

// ---------------- pair GEMM via MFMA: T = D^T D over pair K --------------
__global__ __launch_bounds__(512) void k_pair(const float* __restrict__ emb,
                                              float* __restrict__ part) {
    __shared__ __align__(16) unsigned int dt[2][F_ * LDS_ROW];   // 2 x 10 KB

    const int t    = threadIdx.x;
    const int lane = t & 63;
    const int w    = t >> 6;          // wave 0..7 -> T row-group
    const int i    = t & 127;         // feature (d-gen)
    const int quarter = t >> 7;       // 0..3: k-range quarter*8..+8
    const int halfq   = quarter >> 1;
    const int pbbase  = (quarter & 1) * 8;

    const int fr_row = lane & 15;
    const int fr_k4  = (lane >> 4) * 4;   // dword offset in row

    f32x4 acc[8];
    #pragma unroll
    for (int c = 0; c < 8; ++c) acc[c] = (f32x4)(0.f);

    for (int half = 0; half < 2; ++half) {
        const int L = blockIdx.x + half * NGRID;   // pair-block id 0..527
        int ba = 0, rem = L;
        while (rem >= NBLK - ba) { rem -= NBLK - ba; ++ba; }
        const int bb = ba + rem;
        const bool diag = (ba == bb);

        // hoist all global loads for this half
        float xb[8], xa[8];
        #pragma unroll
        for (int kk = 0; kk < 8; ++kk)
            xb[kk] = emb[(bb * 16 + pbbase + kk) * F_ + i];
        #pragma unroll
        for (int s = 0; s < 8; ++s)
            xa[s] = emb[(ba * 16 + s * 2 + halfq) * F_ + i];

        #pragma unroll 2
        for (int s = 0; s < 8; ++s) {
            const int buf = s & 1;
            const int pa  = s * 2 + halfq;
            unsigned int pk[4];
            #pragma unroll
            for (int q = 0; q < 4; ++q) {
                float d0 = fabsf(xa[s] - xb[2 * q]);
                float d1 = fabsf(xa[s] - xb[2 * q + 1]);
                if (diag && pa >= pbbase + 2 * q)     d0 = 0.f;
                if (diag && pa >= pbbase + 2 * q + 1) d1 = 0.f;
                pk[q] = bf16r(d0) | (bf16r(d1) << 16);
            }
            *reinterpret_cast<uint4*>(&dt[buf][i * LDS_ROW + quarter * 4]) =
                make_uint4(pk[0], pk[1], pk[2], pk[3]);
            __syncthreads();   // single barrier per step (dbuf covers WAR)

            const bf16x8 fA = *reinterpret_cast<const bf16x8*>(
                &dt[buf][(w * 16 + fr_row) * LDS_ROW + fr_k4]);
            #pragma unroll
            for (int c = 0; c < 8; ++c) {
                bf16x8 fB;
                if (c == w) fB = fA;   // wave-uniform; saves 1/9 LDS reads
                else fB = *reinterpret_cast<const bf16x8*>(
                         &dt[buf][(c * 16 + fr_row) * LDS_ROW + fr_k4]);
                acc[c] = __builtin_amdgcn_mfma_f32_16x16x32_bf16(fA, fB, acc[c], 0, 0, 0);
            }
        }
    }

    // epilogue: C layout col=lane&15, row=(lane>>4)*4+reg
    float* dst = part + (size_t)blockIdx.x * (F_ * F_);
    const int r0 = w * 16 + (lane >> 4) * 4;
    const int cj = lane & 15;
    #pragma unroll
    for (int c = 0; c < 8; ++c)
        #pragma unroll
        for (int r = 0; r < 4; ++r)
            dst[(r0 + r) * F_ + c * 16 + cj] = acc[c][r];
}

// -------- reduce partials + corrections; last block finalizes ------------
__global__ __launch_bounds__(256) void k_S_final(const float* __restrict__ part,
                                                 const float* __restrict__ m,
                                                 const float* __restrict__ g,
                                                 const float* __restrict__ tl,
                                                 float* __restrict__ S,
                                                 float* __restrict__ out,
                                                 int* __restrict__ cnt) {
    const int i  = blockIdx.x >> 2;
    const int jq = blockIdx.x & 3;
    const int t  = threadIdx.x;
    const int jl = t & 31;
    const int j  = jq * 32 + jl;
    const int sl = t >> 5;             // 0..7

    float T = 0.f;
    for (int wi = sl * 33; wi < sl * 33 + 33; ++wi)
        T += part[(size_t)wi * (F_ * F_) + i * F_ + j];

    float md = 0.f;
    const float* mi = m + i * B_;
    const float* mj = m + j * B_;
    #pragma unroll 4
    for (int a = sl * 64; a < sl * 64 + 64; ++a) md = fmaf(mi[a], mj[a], md);

    float s_local = 2.0f * T * (1.0f / ((float)B_ * (float)B_))
                  - (2.0f / (float)B_) * md
                  + (sl == 0 ? g[i] * g[j] : 0.f);

    __shared__ float red[256];
    red[t] = s_local;
    __syncthreads();
    if (t < 128) red[t] += red[t + 128];
    __syncthreads();
    if (t < 64) red[t] += red[t + 64];
    __syncthreads();
    if (t < 32) S[i * F_ + j] = red[t] + red[t + 32];

    // ---- last-block finalize (value-deterministic) ----
    __threadfence();          // release: S writes visible before ticket
    __syncthreads();
    __shared__ int ticket;
    if (t == 0) ticket = atomicAdd(cnt, 1);
    __syncthreads();
    if (ticket != (int)gridDim.x - 1) return;
    __threadfence();          // acquire: see all blocks' S

    __shared__ float sq[F_];
    if (t < F_) sq[t] = sqrtf(sqrtf(S[t * F_ + t]));
    __syncthreads();
    float sum = 0.f;
    for (int idx = t; idx < F_ * F_; idx += 256) {
        int ii = idx >> 7, jj = idx & 127;
        if (ii < jj) {
            float sij = S[idx];
            if (sij < 0.f) sij = 0.f;
            sum += sqrtf(sij) / (sq[ii] * sq[jj]);
        }
    }
    red[t] = sum;
    __syncthreads();
    for (int s = 128; s > 0; s >>= 1) {
        if (t < s) red[t] += red[t + s];
        __syncthreads();
    }
    if (t == 0) {
        float corr = red[0] * (1.0f / 8128.0f);   // 128*127/2
        float trip = (tl[0] + tl[1] + tl[2] + tl[3]) * (1.0f / (float)NTRIP);
        out[0] = corr + trip;
    }
}

extern "C" void kernel_launch(void* const* d_in, const int* in_sizes, int n_in,
                              void* d_out, int out_size, void* d_ws, size_t ws_size,
                              hipStream_t stream) {
    const float* emb = (const float*)d_in[0];
    const int*   trp = (const int*)d_in[1];
    float* ws   = (float*)d_ws;
    float* m    = ws + OFF_M;
    float* g    = ws + OFF_G;
    float* tl   = ws + OFF_TL;
    int*   cnt  = (int*)(ws + OFF_CNT);
    float* S    = ws + OFF_S;
    float* part = ws + OFF_PART;
    float* out  = (float*)d_out;

    k_prep   <<<132, 256, 0, stream>>>(emb, trp, m, g, tl, cnt);
    k_pair   <<<NGRID, 512, 0, stream>>>(emb, part);
    k_S_final<<<512, 256, 0, stream>>>(part, m, g, tl, S, out, cnt);
}

// Round 4
// 79.304 us; speedup vs baseline: 1.3597x; 1.3597x over previous
//
#include <hip/hip_runtime.h>
#include <hip/hip_bf16.h>

#define B_    512
#define F_    128
#define NTRIP 1024
#define MARGIN 1.0f
#define NBLK  32      // 512/16 pair-blocks per dim
#define NGRID 264     // k_pair grid: each block folds 2 pair-blocks
#define NG2   24      // stage-1 reduced slab count
#define GSZ   11      // slabs per stage-1 group (24*11 = 264)

// ws layout (floats)
#define OFF_M    0            // 128*512
#define OFF_G    65536        // 128
#define OFF_TL   65664        // 4 triplet partials
#define OFF_S    65680        // 128*128
#define OFF_PART 82064        // 264*16384
#define OFF_P2   (OFF_PART + NGRID * 16384)   // 24*16384

typedef __attribute__((ext_vector_type(8))) short bf16x8;
typedef __attribute__((ext_vector_type(4))) float f32x4;

#define LDS_ROW 20   // dwords per Dt row: 32 bf16 = 16 dwords, +4 pad (80 B)

__device__ inline unsigned int bf16r(float f) {   // RNE float->bf16 (f>=0, finite)
    unsigned int u = __float_as_uint(f);
    u += 0x7FFFu + ((u >> 16) & 1u);
    return u >> 16;
}

// ------------- prep: blocks 0..127 = m/g per feature; 128..131 = triplet ----
__global__ __launch_bounds__(256) void k_prep(const float* __restrict__ emb,
                                              const int* __restrict__ trip,
                                              float* __restrict__ m,
                                              float* __restrict__ g,
                                              float* __restrict__ tl) {
    const int bid = blockIdx.x;
    const int t   = threadIdx.x;
    if (bid < 128) {
        const int i = bid;                      // feature
        __shared__ float x[B_];
        x[t]       = emb[t * F_ + i];
        x[t + 256] = emb[(t + 256) * F_ + i];
        __syncthreads();
        float xa0 = x[t], xa1 = x[t + 256];
        float s0 = 0.f, s1 = 0.f;
        #pragma unroll 4
        for (int b = 0; b < B_; ++b) {
            float xb = x[b];
            s0 += fabsf(xa0 - xb);
            s1 += fabsf(xa1 - xb);
        }
        m[i * B_ + t]       = s0 * (1.0f / B_);
        m[i * B_ + t + 256] = s1 * (1.0f / B_);
        __shared__ float red[256];
        red[t] = s0 + s1;
        __syncthreads();
        for (int s = 128; s > 0; s >>= 1) {
            if (t < s) red[t] += red[t + s];
            __syncthreads();
        }
        if (t == 0) g[i] = red[0] * (1.0f / ((float)B_ * (float)B_));
    } else {
        const int tt = (bid - 128) * 256 + t;   // triplet id 0..1023
        int a = trip[3 * tt]     & (B_ - 1);
        int p = trip[3 * tt + 1] & (B_ - 1);
        int n = trip[3 * tt + 2] & (B_ - 1);
        const float4* ea = reinterpret_cast<const float4*>(emb + a * F_);
        const float4* ep = reinterpret_cast<const float4*>(emb + p * F_);
        const float4* en = reinterpret_cast<const float4*>(emb + n * F_);
        float ap = 0.f, an = 0.f;
        #pragma unroll 8
        for (int f4 = 0; f4 < F_ / 4; ++f4) {
            float4 va = ea[f4], vp = ep[f4], vn = en[f4];
            float d;
            d = va.x - vp.x; ap = fmaf(d, d, ap);
            d = va.y - vp.y; ap = fmaf(d, d, ap);
            d = va.z - vp.z; ap = fmaf(d, d, ap);
            d = va.w - vp.w; ap = fmaf(d, d, ap);
            d = va.x - vn.x; an = fmaf(d, d, an);
            d = va.y - vn.y; an = fmaf(d, d, an);
            d = va.z - vn.z; an = fmaf(d, d, an);
            d = va.w - vn.w; an = fmaf(d, d, an);
        }
        float l = ap - an + MARGIN;
        l = l > 0.f ? l : 0.f;
        __shared__ float red[256];
        red[t] = l;
        __syncthreads();
        for (int s = 128; s > 0; s >>= 1) {
            if (t < s) red[t] += red[t + s];
            __syncthreads();
        }
        if (t == 0) tl[bid - 128] = red[0];
    }
}

// ---------------- pair GEMM via MFMA: T = D^T D over pair K --------------
__global__ __launch_bounds__(512) void k_pair(const float* __restrict__ emb,
                                              float* __restrict__ part) {
    __shared__ __align__(16) unsigned int dt[2][F_ * LDS_ROW];   // 2 x 10 KB

    const int t    = threadIdx.x;
    const int lane = t & 63;
    const int w    = t >> 6;          // wave 0..7 -> T row-group
    const int i    = t & 127;         // feature (d-gen)
    const int quarter = t >> 7;       // 0..3: k-range quarter*8..+8
    const int halfq   = quarter >> 1;
    const int pbbase  = (quarter & 1) * 8;

    const int fr_row = lane & 15;
    const int fr_k4  = (lane >> 4) * 4;   // dword offset in row

    f32x4 acc[8];
    #pragma unroll
    for (int c = 0; c < 8; ++c) acc[c] = (f32x4)(0.f);

    for (int half = 0; half < 2; ++half) {
        const int L = blockIdx.x + half * NGRID;   // pair-block id 0..527
        int ba = 0, rem = L;
        while (rem >= NBLK - ba) { rem -= NBLK - ba; ++ba; }
        const int bb = ba + rem;
        const bool diag = (ba == bb);

        // hoist all global loads for this half
        float xb[8], xa[8];
        #pragma unroll
        for (int kk = 0; kk < 8; ++kk)
            xb[kk] = emb[(bb * 16 + pbbase + kk) * F_ + i];
        #pragma unroll
        for (int s = 0; s < 8; ++s)
            xa[s] = emb[(ba * 16 + s * 2 + halfq) * F_ + i];

        #pragma unroll 2
        for (int s = 0; s < 8; ++s) {
            const int buf = s & 1;
            const int pa  = s * 2 + halfq;
            unsigned int pk[4];
            #pragma unroll
            for (int q = 0; q < 4; ++q) {
                float d0 = fabsf(xa[s] - xb[2 * q]);
                float d1 = fabsf(xa[s] - xb[2 * q + 1]);
                if (diag && pa >= pbbase + 2 * q)     d0 = 0.f;
                if (diag && pa >= pbbase + 2 * q + 1) d1 = 0.f;
                pk[q] = bf16r(d0) | (bf16r(d1) << 16);
            }
            *reinterpret_cast<uint4*>(&dt[buf][i * LDS_ROW + quarter * 4]) =
                make_uint4(pk[0], pk[1], pk[2], pk[3]);
            __syncthreads();   // single barrier per step (dbuf covers WAR)

            const bf16x8 fA = *reinterpret_cast<const bf16x8*>(
                &dt[buf][(w * 16 + fr_row) * LDS_ROW + fr_k4]);
            #pragma unroll
            for (int c = 0; c < 8; ++c) {
                bf16x8 fB;
                if (c == w) fB = fA;   // wave-uniform; saves 1/9 LDS reads
                else fB = *reinterpret_cast<const bf16x8*>(
                         &dt[buf][(c * 16 + fr_row) * LDS_ROW + fr_k4]);
                acc[c] = __builtin_amdgcn_mfma_f32_16x16x32_bf16(fA, fB, acc[c], 0, 0, 0);
            }
        }
    }

    // epilogue: C layout col=lane&15, row=(lane>>4)*4+reg
    float* dst = part + (size_t)blockIdx.x * (F_ * F_);
    const int r0 = w * 16 + (lane >> 4) * 4;
    const int cj = lane & 15;
    #pragma unroll
    for (int c = 0; c < 8; ++c)
        #pragma unroll
        for (int r = 0; r < 4; ++r)
            dst[(r0 + r) * F_ + c * 16 + cj] = acc[c][r];
}

// ------- stage-1 tree reduce: 264 slabs -> 24, contiguous float4 streams ----
__global__ __launch_bounds__(256) void k_S1(const float* __restrict__ part,
                                            float* __restrict__ part2) {
    const int gg  = blockIdx.x >> 5;        // 0..23 slab-group
    const int seg = blockIdx.x & 31;        // 0..31: 512-float segment
    const int t   = threadIdx.x;
    const int c4  = t & 127;                // float4 col within segment
    const int par = t >> 7;                 // wave-uniform parity

    const float4* base = reinterpret_cast<const float4*>(part)
                       + (size_t)(gg * GSZ) * 4096 + seg * 128 + c4;
    float4 a0 = make_float4(0.f, 0.f, 0.f, 0.f);
    float4 a1 = a0;
    #pragma unroll
    for (int k = 0; k < 6; ++k) {
        const int s = par + 2 * k;          // 0,2,..,10 | 1,3,..,9
        if (s < GSZ) {
            float4 v = base[(size_t)s * 4096];
            if (k & 1) { a1.x += v.x; a1.y += v.y; a1.z += v.z; a1.w += v.w; }
            else       { a0.x += v.x; a0.y += v.y; a0.z += v.z; a0.w += v.w; }
        }
    }
    __shared__ float4 sh[256];
    sh[t] = make_float4(a0.x + a1.x, a0.y + a1.y, a0.z + a1.z, a0.w + a1.w);
    __syncthreads();
    if (t < 128) {
        float4 u = sh[t], v = sh[t + 128];
        reinterpret_cast<float4*>(part2)[(size_t)gg * 4096 + seg * 128 + t] =
            make_float4(u.x + v.x, u.y + v.y, u.z + v.z, u.w + v.w);
    }
}

// -------- stage-2: 24 slabs + centering corrections -> S -----------------
__global__ __launch_bounds__(256) void k_S2(const float* __restrict__ part2,
                                            const float* __restrict__ m,
                                            const float* __restrict__ g,
                                            float* __restrict__ S) {
    const int i  = blockIdx.x >> 2;
    const int jq = blockIdx.x & 3;
    const int t  = threadIdx.x;
    const int jl = t & 31;
    const int j  = jq * 32 + jl;
    const int sl = t >> 5;             // 0..7 slices

    float T = 0.f;
    #pragma unroll
    for (int k = 0; k < 3; ++k)
        T += part2[(size_t)(sl * 3 + k) * (F_ * F_) + i * F_ + j];

    float md = 0.f;
    const float* mi = m + i * B_;
    const float* mj = m + j * B_;
    #pragma unroll 4
    for (int a = sl * 64; a < sl * 64 + 64; ++a) md = fmaf(mi[a], mj[a], md);

    float s_local = 2.0f * T * (1.0f / ((float)B_ * (float)B_))
                  - (2.0f / (float)B_) * md
                  + (sl == 0 ? g[i] * g[j] : 0.f);

    __shared__ float red[256];
    red[t] = s_local;
    __syncthreads();
    if (t < 128) red[t] += red[t + 128];
    __syncthreads();
    if (t < 64) red[t] += red[t + 64];
    __syncthreads();
    if (t < 32) S[i * F_ + j] = red[t] + red[t + 32];
}

// ---------------- finalize: corr triu mean + triplet mean ----------------
__global__ __launch_bounds__(256) void k_final(const float* __restrict__ S,
                                               const float* __restrict__ tl,
                                               float* __restrict__ out) {
    const int t = threadIdx.x;
    __shared__ float sq[F_];
    if (t < F_) sq[t] = sqrtf(sqrtf(S[t * F_ + t]));
    __syncthreads();
    float sum = 0.f;
    for (int idx = t; idx < F_ * F_; idx += 256) {
        int i = idx >> 7, j = idx & 127;
        if (i < j) {
            float sij = S[idx];
            if (sij < 0.f) sij = 0.f;
            sum += sqrtf(sij) / (sq[i] * sq[j]);
        }
    }
    __shared__ float red[256];
    red[t] = sum;
    __syncthreads();
    for (int s = 128; s > 0; s >>= 1) {
        if (t < s) red[t] += red[t + s];
        __syncthreads();
    }
    if (t == 0) {
        float corr = red[0] * (1.0f / 8128.0f);   // 128*127/2
        float trip = (tl[0] + tl[1] + tl[2] + tl[3]) * (1.0f / (float)NTRIP);
        out[0] = corr + trip;
    }
}

extern "C" void kernel_launch(void* const* d_in, const int* in_sizes, int n_in,
                              void* d_out, int out_size, void* d_ws, size_t ws_size,
                              hipStream_t stream) {
    const float* emb = (const float*)d_in[0];
    const int*   trp = (const int*)d_in[1];
    float* ws    = (float*)d_ws;
    float* m     = ws + OFF_M;
    float* g     = ws + OFF_G;
    float* tl    = ws + OFF_TL;
    float* S     = ws + OFF_S;
    float* part  = ws + OFF_PART;
    float* part2 = ws + OFF_P2;
    float* out   = (float*)d_out;

    k_prep <<<132, 256, 0, stream>>>(emb, trp, m, g, tl);
    k_pair <<<NGRID, 512, 0, stream>>>(emb, part);
    k_S1   <<<NG2 * 32, 256, 0, stream>>>(part, part2);
    k_S2   <<<512, 256, 0, stream>>>(part2, m, g, S);
    k_final<<<1, 256, 0, stream>>>(S, tl, out);
}